// Round 7
// baseline (121.960 us; speedup 1.0000x reference)
//
#include <hip/hip_runtime.h>
#include <hip/hip_bf16.h>

typedef __attribute__((ext_vector_type(8))) short short8;
typedef __attribute__((ext_vector_type(8))) unsigned short ushort8;
typedef __attribute__((ext_vector_type(4))) unsigned short u16x4;  // NOT "ushort4": HIP predefines that type
typedef __attribute__((ext_vector_type(4))) float f32x4;

#define NB 2
#define NH 12
#define NL 1024
#define NT 1024
#define ND 64
#define NCH 36
#define DIM 768

// round-to-nearest-even f32 -> bf16 bits (inputs finite; no NaN handling needed)
static __device__ __forceinline__ unsigned short f2bf(float x) {
  union { float f; unsigned int u; } c; c.f = x;
  unsigned int r = c.u + 0x7fffu + ((c.u >> 16) & 1u);
  return (unsigned short)(r >> 16);
}

// async global->LDS DMA, 16B per lane. LDS dest rule: HW writes
// readfirstlane(lptr) + lane*16, so lptr must be linear-in-lane stride 16.
static __device__ __forceinline__ void gload_lds16(const float* g, float* l) {
  __builtin_amdgcn_global_load_lds(
      (const __attribute__((address_space(1))) void*)g,
      (__attribute__((address_space(3))) void*)l, 16, 0, 0);
}

// ---------------------------------------------------------------------------
// K1: channel-fuse (36 -> 12) + softmax over T, write attn as bf16.
// One block per (b, l). fuse_b ignored (softmax invariant to per-row const).
//
// R6 -> R7: R5/R6 proved the compiler collapses any register-level load
// pipeline (VGPR stayed ~48-52, 1.2 TB/s, latency-bound). Now scores are
// staged via async global_load_lds (width=16) in double-buffered batches of
// 4 channels (2 x 16 KB LDS). Each wave's DMA dest == the LDS its own lanes
// read, so the main loop is BARRIER-FREE: per-wave counted s_waitcnt
// vmcnt(4) keeps one batch always in flight (T4: never drain to 0).
// sched_barrier(0) after each wait per guide rule #18. Softmax reduction
// reuses the staging LDS -> total 32 KB -> 5 blocks/CU, 20 waves/CU.
// ---------------------------------------------------------------------------
#define K1_ISSUE(BT) do {                                                     \
    gload_lds16(pall[((BT)*4+0)/12] + (size_t)(((BT)*4+0)%12)*NL*NT + t4,     \
                &buf[(BT)&1][0][t4]);                                         \
    gload_lds16(pall[((BT)*4+1)/12] + (size_t)(((BT)*4+1)%12)*NL*NT + t4,     \
                &buf[(BT)&1][1][t4]);                                         \
    gload_lds16(pall[((BT)*4+2)/12] + (size_t)(((BT)*4+2)%12)*NL*NT + t4,     \
                &buf[(BT)&1][2][t4]);                                         \
    gload_lds16(pall[((BT)*4+3)/12] + (size_t)(((BT)*4+3)%12)*NL*NT + t4,     \
                &buf[(BT)&1][3][t4]);                                         \
  } while (0)

#define K1_WAIT4 do { asm volatile("s_waitcnt vmcnt(4)" ::: "memory");        \
                      __builtin_amdgcn_sched_barrier(0); } while (0)
#define K1_WAIT0 do { asm volatile("s_waitcnt vmcnt(0)" ::: "memory");        \
                      __builtin_amdgcn_sched_barrier(0); } while (0)

#define K1_COMP(BT) do {                                                      \
    _Pragma("unroll")                                                         \
    for (int j = 0; j < 4; ++j) {                                             \
      const float4 sv = *(const float4*)&buf[(BT)&1][j][t4];                  \
      const float* wp = wT + ((BT)*4 + j) * NH;                               \
      _Pragma("unroll")                                                       \
      for (int h = 0; h < NH; ++h) {                                          \
        const float w = wp[h];                                                \
        acc[h][0] = fmaf(w, sv.x, acc[h][0]);                                 \
        acc[h][1] = fmaf(w, sv.y, acc[h][1]);                                 \
        acc[h][2] = fmaf(w, sv.z, acc[h][2]);                                 \
        acc[h][3] = fmaf(w, sv.w, acc[h][3]);                                 \
      }                                                                       \
    }                                                                         \
  } while (0)

__global__ __launch_bounds__(256) void k_fuse_softmax(
    const float* __restrict__ s0, const float* __restrict__ s1,
    const float* __restrict__ s2, const float* __restrict__ wT,
    unsigned short* __restrict__ attn)
{
  __shared__ float buf[2][4][NT];   // 32 KiB; reused for reductions after loop
  const int tid = threadIdx.x;
  const int b = blockIdx.x >> 10;
  const int l = blockIdx.x & 1023;
  const int wv = tid >> 6, lane = tid & 63;
  const int t4 = tid * 4;           // 16 B per lane, linear

  float acc[NH][4];
#pragma unroll
  for (int h = 0; h < NH; ++h) {
    acc[h][0] = 0.f; acc[h][1] = 0.f; acc[h][2] = 0.f; acc[h][3] = 0.f;
  }

  const size_t base = (size_t)b * NH * NL * NT + (size_t)l * NT;
  const float* pall[3] = { s0 + base, s1 + base, s2 + base };

  K1_ISSUE(0);
  K1_ISSUE(1); K1_WAIT4; K1_COMP(0);
  K1_ISSUE(2); K1_WAIT4; K1_COMP(1);
  K1_ISSUE(3); K1_WAIT4; K1_COMP(2);
  K1_ISSUE(4); K1_WAIT4; K1_COMP(3);
  K1_ISSUE(5); K1_WAIT4; K1_COMP(4);
  K1_ISSUE(6); K1_WAIT4; K1_COMP(5);
  K1_ISSUE(7); K1_WAIT4; K1_COMP(6);
  K1_ISSUE(8); K1_WAIT4; K1_COMP(7);
  K1_WAIT0;    K1_COMP(8);

  __syncthreads();                  // staging LDS dead; reuse for reductions
  float* red = &buf[0][0][0];       // [0..47] = max partials, [48..95] = sum

  // --- block-wide max per head ---
  float mx[NH];
#pragma unroll
  for (int h = 0; h < NH; ++h) {
    mx[h] = fmaxf(fmaxf(acc[h][0], acc[h][1]), fmaxf(acc[h][2], acc[h][3]));
#pragma unroll
    for (int off = 32; off > 0; off >>= 1)
      mx[h] = fmaxf(mx[h], __shfl_xor(mx[h], off));
  }
  if (lane == 0) {
#pragma unroll
    for (int h = 0; h < NH; ++h) red[wv * NH + h] = mx[h];
  }
  __syncthreads();
#pragma unroll
  for (int h = 0; h < NH; ++h)
    mx[h] = fmaxf(fmaxf(red[0 * NH + h], red[1 * NH + h]),
                  fmaxf(red[2 * NH + h], red[3 * NH + h]));

  // --- exp + block-wide sum per head ---
  float sm[NH];
#pragma unroll
  for (int h = 0; h < NH; ++h) {
    acc[h][0] = __expf(acc[h][0] - mx[h]);
    acc[h][1] = __expf(acc[h][1] - mx[h]);
    acc[h][2] = __expf(acc[h][2] - mx[h]);
    acc[h][3] = __expf(acc[h][3] - mx[h]);
    sm[h] = (acc[h][0] + acc[h][1]) + (acc[h][2] + acc[h][3]);
#pragma unroll
    for (int off = 32; off > 0; off >>= 1)
      sm[h] += __shfl_xor(sm[h], off);
  }
  if (lane == 0) {
#pragma unroll
    for (int h = 0; h < NH; ++h) red[48 + wv * NH + h] = sm[h];
  }
  __syncthreads();

#pragma unroll
  for (int h = 0; h < NH; ++h) {
    float s = (red[48 + 0 * NH + h] + red[48 + 1 * NH + h]) +
              (red[48 + 2 * NH + h] + red[48 + 3 * NH + h]);
    float inv = 1.0f / s;
    u16x4 u;
    u[0] = f2bf(acc[h][0] * inv);
    u[1] = f2bf(acc[h][1] * inv);
    u[2] = f2bf(acc[h][2] * inv);
    u[3] = f2bf(acc[h][3] * inv);
    *(u16x4*)(attn + ((size_t)(b * NH + h) * NL + l) * NT + t4) = u;
  }
}

// ---------------------------------------------------------------------------
// K2a: v (B,H,T,D) f32  ->  vT (B,H,D,T) bf16, via LDS tile transpose.
// Also (block 0 only) writes wT[c][h] = fuse_w[h][c] for K1's SGPR path.
// Runs BEFORE K1.
// ---------------------------------------------------------------------------
__global__ __launch_bounds__(256) void k_transpose_v(
    const float* __restrict__ v, const float* __restrict__ fw,
    unsigned short* __restrict__ vT, float* __restrict__ wT)
{
  __shared__ float vS[128][65];  // +1 pad breaks column-read conflicts
  const int tid = threadIdx.x;
  const int tt = blockIdx.x;   // t-tile of 128
  const int h = blockIdx.y, b = blockIdx.z;
  if (tt == 0 && h == 0 && b == 0) {
    for (int i = tid; i < NCH * NH; i += 256) {   // 432 entries, 256 threads
      int c = i / NH, hh = i % NH;
      wT[c * NH + hh] = fw[hh * NCH + c];
    }
  }
  const int t0 = tt * 128;
  const float* vp = v + ((size_t)(b * NH + h) * NT + t0) * ND;
#pragma unroll
  for (int r = 0; r < 8; ++r) {
    int f = tid + r * 256;            // 2048 float4 chunks
    int t = f >> 4, d4 = (f & 15) * 4;
    float4 x = *(const float4*)(vp + (size_t)t * ND + d4);
    vS[t][d4 + 0] = x.x; vS[t][d4 + 1] = x.y;
    vS[t][d4 + 2] = x.z; vS[t][d4 + 3] = x.w;
  }
  __syncthreads();
  unsigned short* op = vT + (size_t)(b * NH + h) * ND * NT;
#pragma unroll
  for (int r = 0; r < 4; ++r) {
    int c = tid + r * 256;            // 1024 ushort8 chunks
    int d = c >> 4, tl = (c & 15) * 8;
    ushort8 u;
#pragma unroll
    for (int j = 0; j < 8; ++j) u[j] = f2bf(vS[tl + j][d]);
    *(ushort8*)(op + (size_t)d * NT + t0 + tl) = u;
  }
}

// ---------------------------------------------------------------------------
// K2: PV GEMM  x[b,h,l,:] = attn[b,h,l,:] @ v[b,h,:,:]  via bf16 MFMA.
// MFMA 16x16x32 fragment layout (verified passing since R1):
//   A: row = lane&15, k = 8*(lane>>4)+e   (e=0..7, one 16B load)
//   B: col = lane&15, k = 8*(lane>>4)+e   (16B from k-contiguous vT row)
//   C/D: col = lane&15, row = (lane>>4)*4 + reg   [measured m89/m91]
// LDS vS stride 136 ushorts: conflict-free.
// ---------------------------------------------------------------------------
__global__ __launch_bounds__(128) void k_pv(
    const unsigned short* __restrict__ attn,
    const unsigned short* __restrict__ vT,
    unsigned short* __restrict__ xb)
{
  __shared__ unsigned short vS[64][136];
  const int tid = threadIdx.x;
  const int lane = tid & 63, wv = tid >> 6;
  const int lt = blockIdx.x, h = blockIdx.y, b = blockIdx.z;
  const int l0 = lt * 32;
  const unsigned short* ap = attn + ((size_t)(b * NH + h) * NL + l0) * NT;
  const unsigned short* vp = vT + (size_t)(b * NH + h) * ND * NT;
  f32x4 acc[4] = {};
  const int arow = wv * 16 + (lane & 15);
  const int kg = (lane >> 4) * 8;
  const int bn = lane & 15;

  for (int kt = 0; kt < 8; ++kt) {  // k(t)-tiles of 128
    __syncthreads();
#pragma unroll
    for (int r = 0; r < 8; ++r) {   // stage 64 d x 128 t bf16
      int c = tid + r * 128;
      int d = c >> 4, tl = (c & 15) * 8;
      *(ushort8*)&vS[d][tl] = *(const ushort8*)(vp + (size_t)d * NT + kt * 128 + tl);
    }
    __syncthreads();
#pragma unroll
    for (int ks = 0; ks < 4; ++ks) {  // K=32 steps
      short8 af = *(const short8*)(ap + (size_t)arow * NT + kt * 128 + ks * 32 + kg);
#pragma unroll
      for (int dt = 0; dt < 4; ++dt) {
        short8 bf = *(const short8*)&vS[dt * 16 + bn][ks * 32 + kg];
        acc[dt] = __builtin_amdgcn_mfma_f32_16x16x32_bf16(af, bf, acc[dt], 0, 0, 0);
      }
    }
  }
  // write x as bf16 in (B, L, H*D) layout so proj's A is k-contiguous
  const int crow0 = wv * 16 + (lane >> 4) * 4;
#pragma unroll
  for (int dt = 0; dt < 4; ++dt) {
#pragma unroll
    for (int r = 0; r < 4; ++r) {
      int row = l0 + crow0 + r;
      xb[((size_t)b * NL + row) * DIM + h * ND + dt * 16 + bn] = f2bf(acc[dt][r]);
    }
  }
}

// ---------------------------------------------------------------------------
// K3: out[n,o] = sum_k x[n,k] * proj_w[o,k] + proj_b[o], bf16 MFMA, f32 out.
// proj_w is [o][k] row-major == B^T, so B-fragment needs no transpose.
// ---------------------------------------------------------------------------
__global__ __launch_bounds__(256) void k_proj(
    const unsigned short* __restrict__ xb, const float* __restrict__ pw,
    const float* __restrict__ pb, float* __restrict__ out)
{
  __shared__ unsigned short wS[64][136];
  const int tid = threadIdx.x;
  const int lane = tid & 63, wv = tid >> 6;
  const int n0 = blockIdx.x * 64, o0 = blockIdx.y * 64;
  f32x4 acc[4] = {};
  const int kg = (lane >> 4) * 8;
  const int bn = lane & 15;
  const int arow = n0 + wv * 16 + bn;

  for (int kt = 0; kt < 6; ++kt) {  // k-tiles of 128 (768 total)
    __syncthreads();
#pragma unroll
    for (int r = 0; r < 4; ++r) {   // stage W tile 64 o x 128 k as bf16
      int c = tid + r * 256;
      int oi = c >> 4, kl = (c & 15) * 8;
      const float* wp = pw + (size_t)(o0 + oi) * DIM + kt * 128 + kl;
      float4 x0 = *(const float4*)(wp);
      float4 x1 = *(const float4*)(wp + 4);
      ushort8 u;
      u[0] = f2bf(x0.x); u[1] = f2bf(x0.y); u[2] = f2bf(x0.z); u[3] = f2bf(x0.w);
      u[4] = f2bf(x1.x); u[5] = f2bf(x1.y); u[6] = f2bf(x1.z); u[7] = f2bf(x1.w);
      *(ushort8*)&wS[oi][kl] = u;
    }
    __syncthreads();
#pragma unroll
    for (int ks = 0; ks < 4; ++ks) {
      short8 af = *(const short8*)(xb + (size_t)arow * DIM + kt * 128 + ks * 32 + kg);
#pragma unroll
      for (int ot = 0; ot < 4; ++ot) {
        short8 bf = *(const short8*)&wS[ot * 16 + bn][ks * 32 + kg];
        acc[ot] = __builtin_amdgcn_mfma_f32_16x16x32_bf16(af, bf, acc[ot], 0, 0, 0);
      }
    }
  }
  const int crow0 = wv * 16 + (lane >> 4) * 4;
#pragma unroll
  for (int ot = 0; ot < 4; ++ot) {
    const int oc = o0 + ot * 16 + bn;
    const float bias = pb[oc];
#pragma unroll
    for (int r = 0; r < 4; ++r) {
      int row = n0 + crow0 + r;
      out[(size_t)row * DIM + oc] = acc[ot][r] + bias;
    }
  }
}

extern "C" void kernel_launch(void* const* d_in, const int* in_sizes, int n_in,
                              void* d_out, int out_size, void* d_ws, size_t ws_size,
                              hipStream_t stream) {
  const float* s0 = (const float*)d_in[0];
  const float* s1 = (const float*)d_in[1];
  const float* s2 = (const float*)d_in[2];
  const float* v  = (const float*)d_in[3];
  const float* fw = (const float*)d_in[4];
  // d_in[5] = fuse_b: unused — softmax is invariant to a per-row additive bias
  const float* pw = (const float*)d_in[6];
  const float* pb = (const float*)d_in[7];
  float* out = (float*)d_out;

  // workspace layout (bytes):
  //   attn bf16 50,331,648 | vT bf16 3,145,728 | xb bf16 3,145,728 | wT f32 1,728
  const size_t attn_bytes = (size_t)NB * NH * NL * NT * 2;
  const size_t vT_bytes   = (size_t)NB * NH * ND * NT * 2;
  const size_t xb_bytes   = (size_t)NB * NL * DIM * 2;
  unsigned short* attn = (unsigned short*)d_ws;
  unsigned short* vT   = (unsigned short*)((char*)d_ws + attn_bytes);
  unsigned short* xb   = (unsigned short*)((char*)d_ws + attn_bytes + vT_bytes);
  float*          wT   = (float*)((char*)d_ws + attn_bytes + vT_bytes + xb_bytes);

  // k_transpose_v first: it also produces wT, which K1 consumes.
  k_transpose_v<<<dim3(8, NH, NB), dim3(256), 0, stream>>>(v, fw, vT, wT);
  k_fuse_softmax<<<dim3(NB * NL), dim3(256), 0, stream>>>(s0, s1, s2, wT, attn);
  k_pv<<<dim3(32, NH, NB), dim3(128), 0, stream>>>(attn, vT, xb);
  k_proj<<<dim3(32, DIM / 64), dim3(256), 0, stream>>>(xb, pw, pb, out);
}

// Round 8
// 121.732 us; speedup vs baseline: 1.0019x; 1.0019x over previous
//
#include <hip/hip_runtime.h>
#include <hip/hip_bf16.h>

typedef __attribute__((ext_vector_type(8))) short short8;
typedef __attribute__((ext_vector_type(8))) unsigned short ushort8;
typedef __attribute__((ext_vector_type(4))) unsigned short u16x4;  // NOT "ushort4": HIP predefines that type
typedef __attribute__((ext_vector_type(4))) float f32x4;

#define NB 2
#define NH 12
#define NL 1024
#define NT 1024
#define ND 64
#define NCH 36
#define DIM 768

// round-to-nearest-even f32 -> bf16 bits (inputs finite; no NaN handling needed)
static __device__ __forceinline__ unsigned short f2bf(float x) {
  union { float f; unsigned int u; } c; c.f = x;
  unsigned int r = c.u + 0x7fffu + ((c.u >> 16) & 1u);
  return (unsigned short)(r >> 16);
}

// async global->LDS DMA, 16B per lane. LDS dest rule: HW writes
// readfirstlane(lptr) + lane*16, so lptr must be linear-in-lane stride 16.
static __device__ __forceinline__ void gload_lds16(const float* g, float* l) {
  __builtin_amdgcn_global_load_lds(
      (const __attribute__((address_space(1))) void*)g,
      (__attribute__((address_space(3))) void*)l, 16, 0, 0);
}

// ---------------------------------------------------------------------------
// K1: channel-fuse (36 -> 12) + softmax over T, write attn as bf16.
// fuse_b ignored (softmax invariant to a per-row additive constant).
//
// R7 -> R8 (DRAM access-shape rework): R1/R6/R7 all plateaued at ~2.7 TB/s
// effective regardless of structure; on-chip limiters ruled out by
// arithmetic. Theory: ~16K concurrent <=4KB streams (2048 blocks x ~8
// in-flight channels at 4 MiB stride) exceed HBM open-row capacity ->
// row-buffer thrash. This version tiles L by 4: one 1024-thread block per
// (b, 4 rows); wave (r,q) owns quarter-row q of row r; a block reads 16 KB
// CONTIGUOUS per channel-plane, 2 planes in flight (double-buffered LDS,
// barrier-free, per-wave vmcnt(2)). Grid = 512 = fully resident in one
// round; concurrent streams ~1K bursts of 16KB (copy-like shape).
// ---------------------------------------------------------------------------
__global__ __launch_bounds__(1024) void k_fuse_softmax(
    const float* __restrict__ s0, const float* __restrict__ s1,
    const float* __restrict__ s2, const float* __restrict__ wT,
    unsigned short* __restrict__ attn)
{
  __shared__ float buf[2][2][4][NT];   // 64 KiB staging; reused for reductions
  const int tid = threadIdx.x;
  const int wv = tid >> 6, lane = tid & 63;
  const int r = wv >> 2, q = wv & 3;   // row-within-tile, quarter-within-row
  const int b = blockIdx.x >> 8;
  const int l = ((blockIdx.x & 255) << 2) | r;
  const int toff = q * 256 + lane * 4; // this thread's 4 t-elements

  float acc[NH][4];
#pragma unroll
  for (int h = 0; h < NH; ++h) {
    acc[h][0] = 0.f; acc[h][1] = 0.f; acc[h][2] = 0.f; acc[h][3] = 0.f;
  }

  const size_t rowbase = (size_t)b * NH * NL * NT + (size_t)l * NT + toff;
  const float* pall[3] = { s0 + rowbase, s1 + rowbase, s2 + rowbase };

  // channel c: plane pointer (c/12 picks the tensor, c%12 the channel)
#define K1_SRC(c) (pall[(c) / 12] + (size_t)((c) % 12) * NL * NT)

  // prologue: batch 0 (channels 0,1) in flight
  gload_lds16(K1_SRC(0), &buf[0][0][r][toff]);
  gload_lds16(K1_SRC(1), &buf[0][1][r][toff]);

#pragma unroll
  for (int bt = 0; bt < 18; ++bt) {
    if (bt < 17) {
      gload_lds16(K1_SRC(2 * bt + 2), &buf[(bt + 1) & 1][0][r][toff]);
      gload_lds16(K1_SRC(2 * bt + 3), &buf[(bt + 1) & 1][1][r][toff]);
      asm volatile("s_waitcnt vmcnt(2)" ::: "memory");  // batch bt complete
    } else {
      asm volatile("s_waitcnt vmcnt(0)" ::: "memory");  // drain last batch
    }
    __builtin_amdgcn_sched_barrier(0);
#pragma unroll
    for (int j = 0; j < 2; ++j) {
      const int c = 2 * bt + j;
      const float4 sv = *(const float4*)&buf[bt & 1][j][r][toff];
      const float* wp = wT + c * NH;   // uniform addr -> SGPR loads
#pragma unroll
      for (int h = 0; h < NH; ++h) {
        const float w = wp[h];
        acc[h][0] = fmaf(w, sv.x, acc[h][0]);
        acc[h][1] = fmaf(w, sv.y, acc[h][1]);
        acc[h][2] = fmaf(w, sv.z, acc[h][2]);
        acc[h][3] = fmaf(w, sv.w, acc[h][3]);
      }
    }
  }
#undef K1_SRC

  __syncthreads();                     // staging dead; reuse as reduction LDS
  float* red = &buf[0][0][0][0];       // [0..191]=max, [192..383]=sum

  // --- per-row (4 q-waves) max per head ---
  float mx[NH];
#pragma unroll
  for (int h = 0; h < NH; ++h) {
    mx[h] = fmaxf(fmaxf(acc[h][0], acc[h][1]), fmaxf(acc[h][2], acc[h][3]));
#pragma unroll
    for (int off = 32; off > 0; off >>= 1)
      mx[h] = fmaxf(mx[h], __shfl_xor(mx[h], off));
  }
  if (lane == 0) {
#pragma unroll
    for (int h = 0; h < NH; ++h) red[wv * NH + h] = mx[h];
  }
  __syncthreads();
#pragma unroll
  for (int h = 0; h < NH; ++h)
    mx[h] = fmaxf(fmaxf(red[(r * 4 + 0) * NH + h], red[(r * 4 + 1) * NH + h]),
                  fmaxf(red[(r * 4 + 2) * NH + h], red[(r * 4 + 3) * NH + h]));

  // --- exp + per-row sum per head ---
  float sm[NH];
#pragma unroll
  for (int h = 0; h < NH; ++h) {
    acc[h][0] = __expf(acc[h][0] - mx[h]);
    acc[h][1] = __expf(acc[h][1] - mx[h]);
    acc[h][2] = __expf(acc[h][2] - mx[h]);
    acc[h][3] = __expf(acc[h][3] - mx[h]);
    sm[h] = (acc[h][0] + acc[h][1]) + (acc[h][2] + acc[h][3]);
#pragma unroll
    for (int off = 32; off > 0; off >>= 1)
      sm[h] += __shfl_xor(sm[h], off);
  }
  if (lane == 0) {
#pragma unroll
    for (int h = 0; h < NH; ++h) red[192 + wv * NH + h] = sm[h];
  }
  __syncthreads();

#pragma unroll
  for (int h = 0; h < NH; ++h) {
    float s = (red[192 + (r * 4 + 0) * NH + h] + red[192 + (r * 4 + 1) * NH + h]) +
              (red[192 + (r * 4 + 2) * NH + h] + red[192 + (r * 4 + 3) * NH + h]);
    float inv = 1.0f / s;
    u16x4 u;
    u[0] = f2bf(acc[h][0] * inv);
    u[1] = f2bf(acc[h][1] * inv);
    u[2] = f2bf(acc[h][2] * inv);
    u[3] = f2bf(acc[h][3] * inv);
    *(u16x4*)(attn + ((size_t)(b * NH + h) * NL + l) * NT + toff) = u;
  }
}

// ---------------------------------------------------------------------------
// K2a: v (B,H,T,D) f32  ->  vT (B,H,D,T) bf16, via LDS tile transpose.
// Also (block 0 only) writes wT[c][h] = fuse_w[h][c] for K1's SGPR path.
// Runs BEFORE K1.
// ---------------------------------------------------------------------------
__global__ __launch_bounds__(256) void k_transpose_v(
    const float* __restrict__ v, const float* __restrict__ fw,
    unsigned short* __restrict__ vT, float* __restrict__ wT)
{
  __shared__ float vS[128][65];  // +1 pad breaks column-read conflicts
  const int tid = threadIdx.x;
  const int tt = blockIdx.x;   // t-tile of 128
  const int h = blockIdx.y, b = blockIdx.z;
  if (tt == 0 && h == 0 && b == 0) {
    for (int i = tid; i < NCH * NH; i += 256) {   // 432 entries, 256 threads
      int c = i / NH, hh = i % NH;
      wT[c * NH + hh] = fw[hh * NCH + c];
    }
  }
  const int t0 = tt * 128;
  const float* vp = v + ((size_t)(b * NH + h) * NT + t0) * ND;
#pragma unroll
  for (int r = 0; r < 8; ++r) {
    int f = tid + r * 256;            // 2048 float4 chunks
    int t = f >> 4, d4 = (f & 15) * 4;
    float4 x = *(const float4*)(vp + (size_t)t * ND + d4);
    vS[t][d4 + 0] = x.x; vS[t][d4 + 1] = x.y;
    vS[t][d4 + 2] = x.z; vS[t][d4 + 3] = x.w;
  }
  __syncthreads();
  unsigned short* op = vT + (size_t)(b * NH + h) * ND * NT;
#pragma unroll
  for (int r = 0; r < 4; ++r) {
    int c = tid + r * 256;            // 1024 ushort8 chunks
    int d = c >> 4, tl = (c & 15) * 8;
    ushort8 u;
#pragma unroll
    for (int j = 0; j < 8; ++j) u[j] = f2bf(vS[tl + j][d]);
    *(ushort8*)(op + (size_t)d * NT + t0 + tl) = u;
  }
}

// ---------------------------------------------------------------------------
// K2: PV GEMM  x[b,h,l,:] = attn[b,h,l,:] @ v[b,h,:,:]  via bf16 MFMA.
// MFMA 16x16x32 fragment layout (verified passing since R1):
//   A: row = lane&15, k = 8*(lane>>4)+e   (e=0..7, one 16B load)
//   B: col = lane&15, k = 8*(lane>>4)+e   (16B from k-contiguous vT row)
//   C/D: col = lane&15, row = (lane>>4)*4 + reg   [measured m89/m91]
// LDS vS stride 136 ushorts: conflict-free.
// ---------------------------------------------------------------------------
__global__ __launch_bounds__(128) void k_pv(
    const unsigned short* __restrict__ attn,
    const unsigned short* __restrict__ vT,
    unsigned short* __restrict__ xb)
{
  __shared__ unsigned short vS[64][136];
  const int tid = threadIdx.x;
  const int lane = tid & 63, wv = tid >> 6;
  const int lt = blockIdx.x, h = blockIdx.y, b = blockIdx.z;
  const int l0 = lt * 32;
  const unsigned short* ap = attn + ((size_t)(b * NH + h) * NL + l0) * NT;
  const unsigned short* vp = vT + (size_t)(b * NH + h) * ND * NT;
  f32x4 acc[4] = {};
  const int arow = wv * 16 + (lane & 15);
  const int kg = (lane >> 4) * 8;
  const int bn = lane & 15;

  for (int kt = 0; kt < 8; ++kt) {  // k(t)-tiles of 128
    __syncthreads();
#pragma unroll
    for (int r = 0; r < 8; ++r) {   // stage 64 d x 128 t bf16
      int c = tid + r * 128;
      int d = c >> 4, tl = (c & 15) * 8;
      *(ushort8*)&vS[d][tl] = *(const ushort8*)(vp + (size_t)d * NT + kt * 128 + tl);
    }
    __syncthreads();
#pragma unroll
    for (int ks = 0; ks < 4; ++ks) {  // K=32 steps
      short8 af = *(const short8*)(ap + (size_t)arow * NT + kt * 128 + ks * 32 + kg);
#pragma unroll
      for (int dt = 0; dt < 4; ++dt) {
        short8 bf = *(const short8*)&vS[dt * 16 + bn][ks * 32 + kg];
        acc[dt] = __builtin_amdgcn_mfma_f32_16x16x32_bf16(af, bf, acc[dt], 0, 0, 0);
      }
    }
  }
  // write x as bf16 in (B, L, H*D) layout so proj's A is k-contiguous
  const int crow0 = wv * 16 + (lane >> 4) * 4;
#pragma unroll
  for (int dt = 0; dt < 4; ++dt) {
#pragma unroll
    for (int r = 0; r < 4; ++r) {
      int row = l0 + crow0 + r;
      xb[((size_t)b * NL + row) * DIM + h * ND + dt * 16 + bn] = f2bf(acc[dt][r]);
    }
  }
}

// ---------------------------------------------------------------------------
// K3: out[n,o] = sum_k x[n,k] * proj_w[o,k] + proj_b[o], bf16 MFMA, f32 out.
// proj_w is [o][k] row-major == B^T, so B-fragment needs no transpose.
// ---------------------------------------------------------------------------
__global__ __launch_bounds__(256) void k_proj(
    const unsigned short* __restrict__ xb, const float* __restrict__ pw,
    const float* __restrict__ pb, float* __restrict__ out)
{
  __shared__ unsigned short wS[64][136];
  const int tid = threadIdx.x;
  const int lane = tid & 63, wv = tid >> 6;
  const int n0 = blockIdx.x * 64, o0 = blockIdx.y * 64;
  f32x4 acc[4] = {};
  const int kg = (lane >> 4) * 8;
  const int bn = lane & 15;
  const int arow = n0 + wv * 16 + bn;

  for (int kt = 0; kt < 6; ++kt) {  // k-tiles of 128 (768 total)
    __syncthreads();
#pragma unroll
    for (int r = 0; r < 4; ++r) {   // stage W tile 64 o x 128 k as bf16
      int c = tid + r * 256;
      int oi = c >> 4, kl = (c & 15) * 8;
      const float* wp = pw + (size_t)(o0 + oi) * DIM + kt * 128 + kl;
      float4 x0 = *(const float4*)(wp);
      float4 x1 = *(const float4*)(wp + 4);
      ushort8 u;
      u[0] = f2bf(x0.x); u[1] = f2bf(x0.y); u[2] = f2bf(x0.z); u[3] = f2bf(x0.w);
      u[4] = f2bf(x1.x); u[5] = f2bf(x1.y); u[6] = f2bf(x1.z); u[7] = f2bf(x1.w);
      *(ushort8*)&wS[oi][kl] = u;
    }
    __syncthreads();
#pragma unroll
    for (int ks = 0; ks < 4; ++ks) {
      short8 af = *(const short8*)(xb + (size_t)arow * DIM + kt * 128 + ks * 32 + kg);
#pragma unroll
      for (int ot = 0; ot < 4; ++ot) {
        short8 bf = *(const short8*)&wS[ot * 16 + bn][ks * 32 + kg];
        acc[ot] = __builtin_amdgcn_mfma_f32_16x16x32_bf16(af, bf, acc[ot], 0, 0, 0);
      }
    }
  }
  const int crow0 = wv * 16 + (lane >> 4) * 4;
#pragma unroll
  for (int ot = 0; ot < 4; ++ot) {
    const int oc = o0 + ot * 16 + bn;
    const float bias = pb[oc];
#pragma unroll
    for (int r = 0; r < 4; ++r) {
      int row = n0 + crow0 + r;
      out[(size_t)row * DIM + oc] = acc[ot][r] + bias;
    }
  }
}

extern "C" void kernel_launch(void* const* d_in, const int* in_sizes, int n_in,
                              void* d_out, int out_size, void* d_ws, size_t ws_size,
                              hipStream_t stream) {
  const float* s0 = (const float*)d_in[0];
  const float* s1 = (const float*)d_in[1];
  const float* s2 = (const float*)d_in[2];
  const float* v  = (const float*)d_in[3];
  const float* fw = (const float*)d_in[4];
  // d_in[5] = fuse_b: unused — softmax is invariant to a per-row additive bias
  const float* pw = (const float*)d_in[6];
  const float* pb = (const float*)d_in[7];
  float* out = (float*)d_out;

  // workspace layout (bytes):
  //   attn bf16 50,331,648 | vT bf16 3,145,728 | xb bf16 3,145,728 | wT f32 1,728
  const size_t attn_bytes = (size_t)NB * NH * NL * NT * 2;
  const size_t vT_bytes   = (size_t)NB * NH * ND * NT * 2;
  const size_t xb_bytes   = (size_t)NB * NL * DIM * 2;
  unsigned short* attn = (unsigned short*)d_ws;
  unsigned short* vT   = (unsigned short*)((char*)d_ws + attn_bytes);
  unsigned short* xb   = (unsigned short*)((char*)d_ws + attn_bytes + vT_bytes);
  float*          wT   = (float*)((char*)d_ws + attn_bytes + vT_bytes + xb_bytes);

  // k_transpose_v first: it also produces wT, which K1 consumes.
  k_transpose_v<<<dim3(8, NH, NB), dim3(256), 0, stream>>>(v, fw, vT, wT);
  k_fuse_softmax<<<dim3(NB * 256), dim3(1024), 0, stream>>>(s0, s1, s2, wT, attn);
  k_pv<<<dim3(32, NH, NB), dim3(128), 0, stream>>>(attn, vT, xb);
  k_proj<<<dim3(32, DIM / 64), dim3(256), 0, stream>>>(xb, pw, pb, out);
}